// Round 13
// baseline (81.366 us; speedup 1.0000x reference)
//
#include <hip/hip_runtime.h>
#include <hip/hip_bf16.h>
#include <cstdint>
#include <cstddef>

// Problem constants (B=4, H=16, S=4096, E=128)
#define S_LEN 4096
#define E_DIM 128
#define NROWS (4 * 16 * 4096)   // 262144 token rows
#define GRID_MAIN 1024
#define ITERS 4                 // 1024 blk x 4 waves x 16 tok x 4 = NROWS

typedef __attribute__((ext_vector_type(8))) short bh8;   // 8 bf16 MFMA frag
typedef __attribute__((ext_vector_type(4))) short s4;    // 4 bf16
typedef __attribute__((ext_vector_type(4))) float f4;
typedef unsigned short u16;

__device__ __forceinline__ u16 f2bf(float f) {
    union { float f; uint32_t u; } v; v.f = f;
    uint32_t r = v.u + 0x7FFFu + ((v.u >> 16) & 1u);
    return (u16)(r >> 16);
}
__device__ __forceinline__ short bfc(float f) {
    __hip_bfloat16 h = __float2bfloat16(f);
    return *reinterpret_cast<short*>(&h);
}
__device__ __forceinline__ float bf2f(u16 u) {
    union { uint32_t u; float f; } v; v.u = ((uint32_t)u) << 16;
    return v.f;
}
// sin/cos of (rev revolutions): v_fract + v_sin/v_cos
__device__ __forceinline__ void fsincos(float rev, float& sv, float& cv) {
    float r = rev - floorf(rev);
    asm("v_sin_f32 %0, %1" : "=v"(sv) : "v"(r));
    asm("v_cos_f32 %0, %1" : "=v"(cv) : "v"(r));
}

// ============================================================================
// Prologue (1 block): Cayley chain via MFMA (verified R6-R11).
//   A2 = -RR(A,A); A4 = RR(A2,A2); Y1 = A+A2
//   Q  = P - I = 2*(RR(A2,Y1) + RR(A4,Y1) + A2 - A)   (err O(|A|^7))
// ============================================================================
__device__ __forceinline__ bh8 ldsRow(const u16* M, int row, int c) {
    return *(const bh8*)(&M[row * 128 + ((c ^ (row & 15)) * 8)]);
}
__device__ __forceinline__ int swzIdx(int n, int m) {
    return n * 128 + (((m >> 3) ^ (n & 15)) * 8) + (m & 7);
}

__global__ __launch_bounds__(1024) void k_pro(const float* __restrict__ Sc,
        u16* __restrict__ Qb) {
    __shared__ u16 Abf[128 * 128];
    __shared__ u16 A2bf[128 * 128];
    __shared__ u16 Y1bf[128 * 128];
    __shared__ u16 A4bf[128 * 128];

    for (int e = threadIdx.x; e < 16384; e += 1024) {
        int i = e >> 7, j = e & 127;
        float a = 0.5f * (Sc[i * 128 + j] - Sc[j * 128 + i]);
        Abf[swzIdx(i, j)] = f2bf(a);
    }
    __syncthreads();

    const int wave = threadIdx.x >> 6;
    const int lane = threadIdx.x & 63;
    const int lhi = lane >> 4, llo = lane & 15;
    const int sm = wave & 7;
    const int nh = wave >> 3;

    {   // pass 1: A2 = -RR(A,A); Y1 = A + A2
        f4 acc[4];
        #pragma unroll
        for (int t = 0; t < 4; ++t) { f4 z = {0.f,0.f,0.f,0.f}; acc[t] = z; }
        #pragma unroll
        for (int kk = 0; kk < 4; ++kk) {
            bh8 yf = ldsRow(Abf, sm * 16 + llo, kk * 4 + lhi);
            #pragma unroll
            for (int t = 0; t < 4; ++t) {
                bh8 xf = ldsRow(Abf, (nh * 4 + t) * 16 + llo, kk * 4 + lhi);
                acc[t] = __builtin_amdgcn_mfma_f32_16x16x32_bf16(xf, yf, acc[t], 0, 0, 0);
            }
        }
        __syncthreads();
        #pragma unroll
        for (int t = 0; t < 4; ++t)
            #pragma unroll
            for (int r = 0; r < 4; ++r) {
                int n = (nh * 4 + t) * 16 + lhi * 4 + r, m = sm * 16 + llo;
                float a2 = -acc[t][r];
                A2bf[swzIdx(n, m)] = f2bf(a2);
                Y1bf[swzIdx(n, m)] = f2bf(a2 + bf2f(Abf[swzIdx(n, m)]));
            }
    }
    __syncthreads();
    {   // pass 2: A4 = RR(A2,A2)
        f4 acc[4];
        #pragma unroll
        for (int t = 0; t < 4; ++t) { f4 z = {0.f,0.f,0.f,0.f}; acc[t] = z; }
        #pragma unroll
        for (int kk = 0; kk < 4; ++kk) {
            bh8 yf = ldsRow(A2bf, sm * 16 + llo, kk * 4 + lhi);
            #pragma unroll
            for (int t = 0; t < 4; ++t) {
                bh8 xf = ldsRow(A2bf, (nh * 4 + t) * 16 + llo, kk * 4 + lhi);
                acc[t] = __builtin_amdgcn_mfma_f32_16x16x32_bf16(xf, yf, acc[t], 0, 0, 0);
            }
        }
        #pragma unroll
        for (int t = 0; t < 4; ++t)
            #pragma unroll
            for (int r = 0; r < 4; ++r) {
                int n = (nh * 4 + t) * 16 + lhi * 4 + r, m = sm * 16 + llo;
                A4bf[swzIdx(n, m)] = f2bf(acc[t][r]);
            }
    }
    __syncthreads();
    {   // pass 3: Q = 2*(RR(A2,Y1) + RR(A4,Y1) + A2 - A)
        f4 acc[4];
        #pragma unroll
        for (int t = 0; t < 4; ++t) { f4 z = {0.f,0.f,0.f,0.f}; acc[t] = z; }
        #pragma unroll
        for (int kk = 0; kk < 4; ++kk) {
            bh8 yf = ldsRow(Y1bf, sm * 16 + llo, kk * 4 + lhi);
            #pragma unroll
            for (int t = 0; t < 4; ++t) {
                bh8 xf = ldsRow(A2bf, (nh * 4 + t) * 16 + llo, kk * 4 + lhi);
                acc[t] = __builtin_amdgcn_mfma_f32_16x16x32_bf16(xf, yf, acc[t], 0, 0, 0);
            }
        }
        #pragma unroll
        for (int kk = 0; kk < 4; ++kk) {
            bh8 yf = ldsRow(Y1bf, sm * 16 + llo, kk * 4 + lhi);
            #pragma unroll
            for (int t = 0; t < 4; ++t) {
                bh8 xf = ldsRow(A4bf, (nh * 4 + t) * 16 + llo, kk * 4 + lhi);
                acc[t] = __builtin_amdgcn_mfma_f32_16x16x32_bf16(xf, yf, acc[t], 0, 0, 0);
            }
        }
        #pragma unroll
        for (int t = 0; t < 4; ++t)
            #pragma unroll
            for (int r = 0; r < 4; ++r) {
                int n = (nh * 4 + t) * 16 + lhi * 4 + r, m = sm * 16 + llo;
                float q = 2.0f * (acc[t][r] + bf2f(A2bf[swzIdx(n, m)])
                                            - bf2f(Abf[swzIdx(n, m)]));
                Qb[n * 128 + m] = f2bf(q);
            }
    }
}

// ============================================================================
// One iteration: copy-shaped loads, bf16 transpose-in scratch, MFMA from
// swizzled-Q LDS, acc-layout epilogue with in-register sincos, plain stores.
// xs is reloaded at the end with it+2's x (youngest VMEM; full-iter slack).
// ============================================================================
__device__ __forceinline__ void iter_body(int it, f4 (&xs)[8],
        const float* __restrict__ x, const float* __restrict__ pos,
        float* __restrict__ out, const u16* Plds, u16* myscr,
        const float (&frev)[8], int wbase0, int half, int c, int lhi, int llo) {
    const int wbase = wbase0 + it * 64;
    const int m = wbase + llo;               // this lane's token (acc layout)
    const int s = m & (S_LEN - 1);
    const float p = pos[s];                  // 64B contiguous per wave, L1-hot

    // [1] transpose-in: xs (f32 store layout) -> bf16 scratch (pair-swizzled)
    #pragma unroll
    for (int j = 0; j < 8; ++j) {
        const int tok = 2 * j + half;
        const int q = c >> 1;
        s4 v;
        v[0] = bfc(xs[j][0]); v[1] = bfc(xs[j][1]);
        v[2] = bfc(xs[j][2]); v[3] = bfc(xs[j][3]);
        *(s4*)(&myscr[tok * 128 + ((q ^ tok) & 15) * 8 + (c & 1) * 4]) = v;
    }
    __builtin_amdgcn_sched_barrier(0);

    // [2] MFMA: acc[t] = (x*Q^T)[tok=llo][n=t*16+lhi*4+r]
    f4 acc[8];
    #pragma unroll
    for (int t = 0; t < 8; ++t) { f4 z = {0.f, 0.f, 0.f, 0.f}; acc[t] = z; }
    #pragma unroll
    for (int kk = 0; kk < 4; ++kk) {
        const int pc = (kk * 4 + lhi) ^ llo;
        bh8 frag = *(const bh8*)(&myscr[llo * 128 + pc * 8]);
        #pragma unroll
        for (int t = 0; t < 8; ++t) {
            bh8 qfrag = *(const bh8*)(&Plds[(t * 16 + llo) * 128 + pc * 8]);
            acc[t] = __builtin_amdgcn_mfma_f32_16x16x32_bf16(qfrag, frag, acc[t], 0, 0, 0);
        }
    }
    __builtin_amdgcn_sched_barrier(0);

    // [3] epilogue in acc layout: xt = acc + x(scr), in-register RoPE, store
    float* orow = out + (size_t)m * E_DIM;
    #pragma unroll
    for (int t = 0; t < 4; ++t) {
        const int n0 = t * 16 + lhi * 4;
        const int q_lo = t * 2 + (lhi >> 1);
        const int sub = (lhi & 1) * 4;
        s4 xbl = *(const s4*)(&myscr[llo * 128 + ((q_lo ^ llo) & 15) * 8 + sub]);
        s4 xbh = *(const s4*)(&myscr[llo * 128 + (((q_lo + 8) ^ llo) & 15) * 8 + sub]);
        // sincos for f = t*8+lhi*2 (+1), and +32 (freq*0.01)
        float sa0, ca0, sa1, ca1, sh0, ch0, sh1, ch1;
        float r0 = p * frev[t * 2], r1 = p * frev[t * 2 + 1];
        fsincos(r0, sa0, ca0);
        fsincos(r1, sa1, ca1);
        fsincos(r0 * 0.01f, sh0, ch0);
        fsincos(r1 * 0.01f, sh1, ch1);
        f4 olo, ohi;
        #pragma unroll
        for (int r = 0; r < 4; ++r) {
            float xt1 = acc[t][r]     + bf2f((u16)xbl[r]);   // n = n0+r
            float xt2 = acc[t + 4][r] + bf2f((u16)xbh[r]);   // n+64
            float cv = (r < 2) ? ca0 : ca1, sv = (r < 2) ? sa0 : sa1;
            float cvh = (r < 2) ? ch0 : ch1, svh = (r < 2) ? sh0 : sh1;
            olo[r] = xt1 * cv - xt2 * sv;
            ohi[r] = xt2 * cvh + xt1 * svh;
        }
        *(f4*)(orow + n0) = olo;             // 64B segs; L2 merges full lines
        *(f4*)(orow + n0 + 64) = ohi;
    }
    __builtin_amdgcn_sched_barrier(0);

    // [4] reload xs with it+2's x — youngest VMEM, lands during iter it+1
    if (it + 2 < ITERS) {
        const float* xb = x + (size_t)(wbase + 128) * E_DIM;
        #pragma unroll
        for (int j = 0; j < 8; ++j)
            xs[j] = *(const f4*)(xb + (2 * j + half) * E_DIM + 4 * c);
    }
}

__global__ __launch_bounds__(256, 3) void k_main(const float* __restrict__ x,
        const u16* __restrict__ Qb, const float* __restrict__ pos,
        float* __restrict__ out) {
    __shared__ u16 Plds[128 * 128];      // 32 KB Q (swizzled)
    __shared__ u16 scr[4][16 * 128];     // 16 KB: per-wave 4 KB bf16 x-tile

    const int wave = threadIdx.x >> 6;
    const int lane = threadIdx.x & 63;
    const int lhi = (lane >> 4) & 3, llo = lane & 15;
    const int half = lane >> 5;          // which of the 2 tokens per load inst
    const int c = lane & 31;             // 16B chunk within token row
    const int wbase0 = blockIdx.x * (64 * ITERS) + wave * 16;

    // preload iters 0,1 (copy-shaped: 1KB contiguous per instruction)
    f4 xsA[8], xsB[8];
    {
        const float* xb = x + (size_t)wbase0 * E_DIM;
        #pragma unroll
        for (int j = 0; j < 8; ++j)
            xsA[j] = *(const f4*)(xb + (2 * j + half) * E_DIM + 4 * c);
        const float* xb1 = x + (size_t)(wbase0 + 64) * E_DIM;
        #pragma unroll
        for (int j = 0; j < 8; ++j)
            xsB[j] = *(const f4*)(xb1 + (2 * j + half) * E_DIM + 4 * c);
    }

    // stage Q once (chunk cc of row at cc ^ (row&15))
    #pragma unroll
    for (int i = 0; i < 8; ++i) {
        int chunk = i * 256 + threadIdx.x;
        int row = chunk >> 4, cc = chunk & 15;
        int pc = cc ^ (row & 15);
        bh8 v = *(const bh8*)(Qb + chunk * 8);
        *(bh8*)(&Plds[row * 128 + pc * 8]) = v;
    }

    // per-lane rotation frequencies (revolutions): f = t*8 + lhi*2 + b
    float frev[8];
    #pragma unroll
    for (int t = 0; t < 4; ++t)
        #pragma unroll
        for (int b = 0; b < 2; ++b)
            frev[t * 2 + b] = exp2f(-0.20762050593046015f * (float)(t * 8 + lhi * 2 + b))
                              * 0.15915494309189535f;   // /2pi

    __syncthreads();   // Q staged

    u16* myscr = scr[wave];
    #pragma unroll 1
    for (int it2 = 0; it2 < ITERS; it2 += 2) {
        iter_body(it2,     xsA, x, pos, out, Plds, myscr, frev, wbase0, half, c, lhi, llo);
        iter_body(it2 + 1, xsB, x, pos, out, Plds, myscr, frev, wbase0, half, c, lhi, llo);
    }
}

extern "C" void kernel_launch(void* const* d_in, const int* in_sizes, int n_in,
                              void* d_out, int out_size, void* d_ws, size_t ws_size,
                              hipStream_t stream) {
    const float* x   = (const float*)d_in[0];
    const float* pos = (const float*)d_in[1];
    const float* Sc  = (const float*)d_in[2];
    float* out = (float*)d_out;

    u16* Qb = (u16*)d_ws;                  // 32 KB bf16 Q = P - I

    k_pro<<<1, 1024, 0, stream>>>(Sc, Qb);
    k_main<<<GRID_MAIN, 256, 0, stream>>>(x, Qb, pos, out);
}

// Round 14
// 61.841 us; speedup vs baseline: 1.3157x; 1.3157x over previous
//
#include <hip/hip_runtime.h>
#include <hip/hip_bf16.h>
#include <cstdint>
#include <cstddef>

// Problem constants (B=4, H=16, S=4096, E=128)
#define S_LEN 4096
#define E_DIM 128
#define NROWS (4 * 16 * 4096)   // 262144 token rows
#define GRID_MAIN 512
#define ITERS 8                 // 512 blk x 4 waves x 16 tok x 8 = NROWS

typedef __attribute__((ext_vector_type(8))) short bh8;   // 8 bf16 MFMA frag
typedef __attribute__((ext_vector_type(4))) float f4;
typedef unsigned short u16;

__device__ __forceinline__ u16 f2bf(float f) {
    union { float f; uint32_t u; } v; v.f = f;
    uint32_t r = v.u + 0x7FFFu + ((v.u >> 16) & 1u);
    return (u16)(r >> 16);
}
__device__ __forceinline__ short bfc(float f) {
    __hip_bfloat16 h = __float2bfloat16(f);
    return *reinterpret_cast<short*>(&h);
}
__device__ __forceinline__ float bf2f(u16 u) {
    union { uint32_t u; float f; } v; v.u = ((uint32_t)u) << 16;
    return v.f;
}
// sin/cos of (rev revolutions): v_fract + v_sin/v_cos (only used OUTSIDE loop)
__device__ __forceinline__ void fsincos(float rev, float& sv, float& cv) {
    float r = rev - floorf(rev);
    asm("v_sin_f32 %0, %1" : "=v"(sv) : "v"(r));
    asm("v_cos_f32 %0, %1" : "=v"(cv) : "v"(r));
}

// ============================================================================
// Prologue (1 block): Cayley chain via MFMA (verified R6-R12).
//   A2 = -RR(A,A); A4 = RR(A2,A2); Y1 = A+A2
//   Q  = P - I = 2*(RR(A2,Y1) + RR(A4,Y1) + A2 - A)   (err O(|A|^7))
// ============================================================================
__device__ __forceinline__ bh8 ldsRow(const u16* M, int row, int c) {
    return *(const bh8*)(&M[row * 128 + ((c ^ (row & 15)) * 8)]);
}
__device__ __forceinline__ int swzIdx(int n, int m) {
    return n * 128 + (((m >> 3) ^ (n & 15)) * 8) + (m & 7);
}

__global__ __launch_bounds__(1024) void k_pro(const float* __restrict__ Sc,
        u16* __restrict__ Qb) {
    __shared__ u16 Abf[128 * 128];
    __shared__ u16 A2bf[128 * 128];
    __shared__ u16 Y1bf[128 * 128];
    __shared__ u16 A4bf[128 * 128];

    for (int e = threadIdx.x; e < 16384; e += 1024) {
        int i = e >> 7, j = e & 127;
        float a = 0.5f * (Sc[i * 128 + j] - Sc[j * 128 + i]);
        Abf[swzIdx(i, j)] = f2bf(a);
    }
    __syncthreads();

    const int wave = threadIdx.x >> 6;
    const int lane = threadIdx.x & 63;
    const int lhi = lane >> 4, llo = lane & 15;
    const int sm = wave & 7;
    const int nh = wave >> 3;

    {   // pass 1: A2 = -RR(A,A); Y1 = A + A2
        f4 acc[4];
        #pragma unroll
        for (int t = 0; t < 4; ++t) { f4 z = {0.f,0.f,0.f,0.f}; acc[t] = z; }
        #pragma unroll
        for (int kk = 0; kk < 4; ++kk) {
            bh8 yf = ldsRow(Abf, sm * 16 + llo, kk * 4 + lhi);
            #pragma unroll
            for (int t = 0; t < 4; ++t) {
                bh8 xf = ldsRow(Abf, (nh * 4 + t) * 16 + llo, kk * 4 + lhi);
                acc[t] = __builtin_amdgcn_mfma_f32_16x16x32_bf16(xf, yf, acc[t], 0, 0, 0);
            }
        }
        __syncthreads();
        #pragma unroll
        for (int t = 0; t < 4; ++t)
            #pragma unroll
            for (int r = 0; r < 4; ++r) {
                int n = (nh * 4 + t) * 16 + lhi * 4 + r, m = sm * 16 + llo;
                float a2 = -acc[t][r];
                A2bf[swzIdx(n, m)] = f2bf(a2);
                Y1bf[swzIdx(n, m)] = f2bf(a2 + bf2f(Abf[swzIdx(n, m)]));
            }
    }
    __syncthreads();
    {   // pass 2: A4 = RR(A2,A2)
        f4 acc[4];
        #pragma unroll
        for (int t = 0; t < 4; ++t) { f4 z = {0.f,0.f,0.f,0.f}; acc[t] = z; }
        #pragma unroll
        for (int kk = 0; kk < 4; ++kk) {
            bh8 yf = ldsRow(A2bf, sm * 16 + llo, kk * 4 + lhi);
            #pragma unroll
            for (int t = 0; t < 4; ++t) {
                bh8 xf = ldsRow(A2bf, (nh * 4 + t) * 16 + llo, kk * 4 + lhi);
                acc[t] = __builtin_amdgcn_mfma_f32_16x16x32_bf16(xf, yf, acc[t], 0, 0, 0);
            }
        }
        #pragma unroll
        for (int t = 0; t < 4; ++t)
            #pragma unroll
            for (int r = 0; r < 4; ++r) {
                int n = (nh * 4 + t) * 16 + lhi * 4 + r, m = sm * 16 + llo;
                A4bf[swzIdx(n, m)] = f2bf(acc[t][r]);
            }
    }
    __syncthreads();
    {   // pass 3: Q = 2*(RR(A2,Y1) + RR(A4,Y1) + A2 - A)
        f4 acc[4];
        #pragma unroll
        for (int t = 0; t < 4; ++t) { f4 z = {0.f,0.f,0.f,0.f}; acc[t] = z; }
        #pragma unroll
        for (int kk = 0; kk < 4; ++kk) {
            bh8 yf = ldsRow(Y1bf, sm * 16 + llo, kk * 4 + lhi);
            #pragma unroll
            for (int t = 0; t < 4; ++t) {
                bh8 xf = ldsRow(A2bf, (nh * 4 + t) * 16 + llo, kk * 4 + lhi);
                acc[t] = __builtin_amdgcn_mfma_f32_16x16x32_bf16(xf, yf, acc[t], 0, 0, 0);
            }
        }
        #pragma unroll
        for (int kk = 0; kk < 4; ++kk) {
            bh8 yf = ldsRow(Y1bf, sm * 16 + llo, kk * 4 + lhi);
            #pragma unroll
            for (int t = 0; t < 4; ++t) {
                bh8 xf = ldsRow(A4bf, (nh * 4 + t) * 16 + llo, kk * 4 + lhi);
                acc[t] = __builtin_amdgcn_mfma_f32_16x16x32_bf16(xf, yf, acc[t], 0, 0, 0);
            }
        }
        #pragma unroll
        for (int t = 0; t < 4; ++t)
            #pragma unroll
            for (int r = 0; r < 4; ++r) {
                int n = (nh * 4 + t) * 16 + lhi * 4 + r, m = sm * 16 + llo;
                float q = 2.0f * (acc[t][r] + bf2f(A2bf[swzIdx(n, m)])
                                            - bf2f(Abf[swzIdx(n, m)]));
                Qb[n * 128 + m] = f2bf(q);
            }
    }
}

// ============================================================================
// One iteration (R11 structure verbatim except: cs table loads replaced by
// in-register complex recurrence; x reload is now it+3 -> depth-3 prefetch).
// zi = {cosA, sinA, cosB, sinB} at s = wbase + half for this lane's 2 freqs.
// r2 = rotator for s+=2 (per-j step); r64 = rotator for s+=64 (per-iter step).
// ============================================================================
template <int IT>
__device__ __forceinline__ void iter_body(f4 (&xs)[8], float (&zi)[4],
        const float (&r2)[4], const float (&r64)[4],
        const float* __restrict__ x, float* __restrict__ out,
        const u16* Plds, f4* scr,
        int wbase0, int half, int c, int lhi, int llo, float sg) {
    const int wbase = wbase0 + IT * 64;

    // [1] transpose-in: xs -> scratch (swizzled), read back as frags
    #pragma unroll
    for (int j = 0; j < 8; ++j) {
        int tk = 2 * j + half;
        scr[tk * 32 + (c ^ tk)] = xs[j];
    }
    bh8 frag[4];
    #pragma unroll
    for (int kk = 0; kk < 4; ++kk) {
        int ch0 = kk * 8 + lhi * 2;
        f4 v0 = scr[llo * 32 + (ch0 ^ llo)];
        f4 v1 = scr[llo * 32 + ((ch0 + 1) ^ llo)];
        bh8 a;
        #pragma unroll
        for (int e = 0; e < 4; ++e) { a[e] = bfc(v0[e]); a[4 + e] = bfc(v1[e]); }
        frag[kk] = a;
    }
    __builtin_amdgcn_sched_barrier(0);

    // [2] MFMA: acc[t] = (x*Q^T)[token=llo][n=t*16+lhi*4+r]
    f4 acc[8];
    #pragma unroll
    for (int t = 0; t < 8; ++t) { f4 z = {0.f, 0.f, 0.f, 0.f}; acc[t] = z; }
    #pragma unroll
    for (int kk = 0; kk < 4; ++kk) {
        #pragma unroll
        for (int t = 0; t < 8; ++t) {
            int pc = (kk * 4 + lhi) ^ llo;
            bh8 qfrag = *(const bh8*)(&Plds[(t * 16 + llo) * 128 + pc * 8]);
            acc[t] = __builtin_amdgcn_mfma_f32_16x16x32_bf16(qfrag, frag[kk], acc[t], 0, 0, 0);
        }
    }

    // [3] transpose-out: acc -> scratch -> store layout
    #pragma unroll
    for (int t = 0; t < 4; ++t) {
        scr[llo * 32 + ((t * 4 + lhi) ^ llo)]      = acc[t];
        scr[llo * 32 + ((16 + t * 4 + lhi) ^ llo)] = acc[t + 4];
    }
    f4 os[8];
    #pragma unroll
    for (int j = 0; j < 8; ++j) {
        int tk = 2 * j + half;
        os[j] = scr[tk * 32 + (c ^ tk)];
    }

    // [4] epilogue: xt = os + x; rotate-half via shfl_xor; cos/sin via
    //     in-register complex recurrence (VALU only); nt 1KB stores
    float zc0 = zi[0], zs0 = zi[1], zc1 = zi[2], zs1 = zi[3];
    float* ob = out + (size_t)wbase * E_DIM;
    #pragma unroll
    for (int j = 0; j < 8; ++j) {
        f4 xt, xp, o;
        #pragma unroll
        for (int e = 0; e < 4; ++e) xt[e] = os[j][e] + xs[j][e];
        #pragma unroll
        for (int e = 0; e < 4; ++e) xp[e] = __shfl_xor(xt[e], 16, 64);
        o[0] = xt[0] * zc0 + sg * xp[0] * zs0;
        o[1] = xt[1] * zc0 + sg * xp[1] * zs0;
        o[2] = xt[2] * zc1 + sg * xp[2] * zs1;
        o[3] = xt[3] * zc1 + sg * xp[3] * zs1;
        __builtin_nontemporal_store(o, (f4*)(ob + (2 * j + half) * E_DIM + 4 * c));
        // advance z by 2 positions (rotator r2)
        float t0 = zc0 * r2[0] - zs0 * r2[1];
        zs0 = zc0 * r2[1] + zs0 * r2[0]; zc0 = t0;
        float t1 = zc1 * r2[2] - zs1 * r2[3];
        zs1 = zc1 * r2[3] + zs1 * r2[2]; zc1 = t1;
    }
    // advance iter-base z by 64 positions (rotator r64)
    { float t = zi[0] * r64[0] - zi[1] * r64[1];
      zi[1] = zi[0] * r64[1] + zi[1] * r64[0]; zi[0] = t; }
    { float t = zi[2] * r64[2] - zi[3] * r64[3];
      zi[3] = zi[2] * r64[3] + zi[3] * r64[2]; zi[2] = t; }
    __builtin_amdgcn_sched_barrier(0);

    // [5] reload xs with IT+3's x — youngest VMEM, ~2 iterations of slack
    if constexpr (IT + 3 < ITERS) {
        const float* xb = x + (size_t)(wbase + 192) * E_DIM;
        #pragma unroll
        for (int j = 0; j < 8; ++j)
            xs[j] = *(const f4*)(xb + (2 * j + half) * E_DIM + 4 * c);
    }
}

__global__ __launch_bounds__(256, 2) void k_main(const float* __restrict__ x,
        const u16* __restrict__ Qb, float* __restrict__ out) {
    __shared__ u16 Plds[128 * 128];      // 32 KB Q (swizzled)
    __shared__ f4 scratch[4][16 * 32];   // 32 KB: per-wave 16 tok x 32 chunks

    // stage Q once (chunk cc of row at cc ^ (row&15))
    #pragma unroll
    for (int i = 0; i < 8; ++i) {
        int chunk = i * 256 + threadIdx.x;
        int row = chunk >> 4, cc = chunk & 15;
        int pc = cc ^ (row & 15);
        bh8 v = *(const bh8*)(Qb + chunk * 8);
        *(bh8*)(&Plds[row * 128 + pc * 8]) = v;
    }

    const int wave = threadIdx.x >> 6;
    const int lane = threadIdx.x & 63;
    const int lhi = (lane >> 4) & 3, llo = lane & 15;
    const int half = lane >> 5;          // which of the 2 tokens per load inst
    const int c = lane & 31;             // 16B chunk within token row
    f4* scr = scratch[wave];

    const int wbase0 = blockIdx.x * 512 + wave * 16;
    const float sg = (lane & 16) ? 1.0f : -1.0f;   // rotate-half sign

    // rotation state: lane's 2 freqs f = 2c, 2c+1 (revolutions per position)
    float zi[4], r2[4], r64[4];
    {
        const float wa = exp2f(-0.20762050593046015f * (float)(2 * c))
                         * 0.15915494309189535f;          // 10000^(-2c/64)/2pi
        const float wb = wa * 0.8659643233600653f;        // * 10000^(-1/64)
        const float s0 = (float)((wbase0 + half) & (S_LEN - 1));
        fsincos(s0 * wa, zi[1], zi[0]);
        fsincos(s0 * wb, zi[3], zi[2]);
        fsincos(2.0f * wa, r2[1], r2[0]);
        fsincos(2.0f * wb, r2[3], r2[2]);
        fsincos(64.0f * wa, r64[1], r64[0]);
        fsincos(64.0f * wb, r64[3], r64[2]);
    }

    // preload iters 0,1,2 (copy-shaped: 1KB contiguous per instruction)
    f4 xsA[8], xsB[8], xsC[8];
    {
        const float* xb0 = x + (size_t)wbase0 * E_DIM;
        const float* xb1 = xb0 + 64 * E_DIM;
        const float* xb2 = xb0 + 128 * E_DIM;
        #pragma unroll
        for (int j = 0; j < 8; ++j)
            xsA[j] = *(const f4*)(xb0 + (2 * j + half) * E_DIM + 4 * c);
        #pragma unroll
        for (int j = 0; j < 8; ++j)
            xsB[j] = *(const f4*)(xb1 + (2 * j + half) * E_DIM + 4 * c);
        #pragma unroll
        for (int j = 0; j < 8; ++j)
            xsC[j] = *(const f4*)(xb2 + (2 * j + half) * E_DIM + 4 * c);
    }
    __syncthreads();   // Q staged

    iter_body<0>(xsA, zi, r2, r64, x, out, Plds, scr, wbase0, half, c, lhi, llo, sg);
    iter_body<1>(xsB, zi, r2, r64, x, out, Plds, scr, wbase0, half, c, lhi, llo, sg);
    iter_body<2>(xsC, zi, r2, r64, x, out, Plds, scr, wbase0, half, c, lhi, llo, sg);
    iter_body<3>(xsA, zi, r2, r64, x, out, Plds, scr, wbase0, half, c, lhi, llo, sg);
    iter_body<4>(xsB, zi, r2, r64, x, out, Plds, scr, wbase0, half, c, lhi, llo, sg);
    iter_body<5>(xsC, zi, r2, r64, x, out, Plds, scr, wbase0, half, c, lhi, llo, sg);
    iter_body<6>(xsA, zi, r2, r64, x, out, Plds, scr, wbase0, half, c, lhi, llo, sg);
    iter_body<7>(xsB, zi, r2, r64, x, out, Plds, scr, wbase0, half, c, lhi, llo, sg);
}

extern "C" void kernel_launch(void* const* d_in, const int* in_sizes, int n_in,
                              void* d_out, int out_size, void* d_ws, size_t ws_size,
                              hipStream_t stream) {
    const float* x   = (const float*)d_in[0];
    const float* pos = (const float*)d_in[1];
    const float* Sc  = (const float*)d_in[2];
    float* out = (float*)d_out;
    (void)pos;

    u16* Qb = (u16*)d_ws;                  // 32 KB bf16 Q = P - I

    k_pro<<<1, 1024, 0, stream>>>(Sc, Qb);
    k_main<<<GRID_MAIN, 256, 0, stream>>>(x, Qb, out);
}